// Round 10
// baseline (221.280 us; speedup 1.0000x reference)
//
#include <hip/hip_runtime.h>

typedef __attribute__((ext_vector_type(8))) __bf16 bf16x8;
typedef __attribute__((ext_vector_type(4))) float f32x4;
typedef const __attribute__((address_space(1))) unsigned int gas_u32;
typedef __attribute__((address_space(3))) unsigned int las_u32;

__device__ __forceinline__ unsigned short f2bf(float f) {
  unsigned u = __builtin_bit_cast(unsigned, f);
  u = (u + 0x7FFFu + ((u >> 16) & 1u)) >> 16;
  return (unsigned short)u;
}
__device__ __forceinline__ float bf2f(unsigned short h) {
  return __builtin_bit_cast(float, (unsigned)h << 16);
}

// ---------- merged prep: f32->bf16 converts (+ sum-of-squares for the two weights) ----
__global__ __launch_bounds__(256) void k_prep(
    const float* __restrict__ v, const float* __restrict__ q,
    const float* __restrict__ vw, const float* __restrict__ qw,
    unsigned short* __restrict__ v_bf, unsigned short* __restrict__ q_bf,
    unsigned short* __restrict__ vw_bf, unsigned short* __restrict__ qw_bf,
    float* __restrict__ ss) {
  __shared__ float red[4];
  int bid = blockIdx.x, tid = threadIdx.x;
  const float* in;
  unsigned short* out;
  float* ssout = nullptr;
  int n8, b0, nb;
  if (bid < 896) {
    in = v; out = v_bf; n8 = 2097152; b0 = bid; nb = 896;
  } else if (bid < 1008) {
    in = q; out = q_bf; n8 = 262144; b0 = bid - 896; nb = 112;
  } else if (bid < 1360) {
    in = vw; out = vw_bf; n8 = 786432; b0 = bid - 1008; nb = 352; ssout = ss + 0;
  } else {
    in = qw; out = qw_bf; n8 = 393216; b0 = bid - 1360; nb = 176; ssout = ss + 1;
  }
  float s = 0.f;
  for (int i = b0 * 256 + tid; i < n8; i += nb * 256) {
    float4 a = ((const float4*)in)[2 * i];
    float4 b = ((const float4*)in)[2 * i + 1];
    if (ssout) {
      s += a.x * a.x + a.y * a.y + a.z * a.z + a.w * a.w;
      s += b.x * b.x + b.y * b.y + b.z * b.z + b.w * b.w;
    }
    uint4 o;
    o.x = f2bf(a.x) | ((unsigned)f2bf(a.y) << 16);
    o.y = f2bf(a.z) | ((unsigned)f2bf(a.w) << 16);
    o.z = f2bf(b.x) | ((unsigned)f2bf(b.y) << 16);
    o.w = f2bf(b.z) | ((unsigned)f2bf(b.w) << 16);
    ((uint4*)out)[i] = o;
  }
  if (ssout) {
    for (int off = 32; off; off >>= 1) s += __shfl_down(s, off);
    if ((tid & 63) == 0) red[tid >> 6] = s;
    __syncthreads();
    if (tid == 0) atomicAdd(ssout, red[0] + red[1] + red[2] + red[3]);
  }
}

// ======== merged GEMM: 256x256 tile, 8 waves (2Mx4N, wave 128x64), R8 rotation ========
// WHY: LDS-port roofline. 64x96 waves = 427 B read/MFMA -> 38% MfmaUtil ceiling (the
// 7-round plateau). 128x64 waves = 384 B/MFMA + halved DMA-write share -> ~60% ceiling
// (m201's measured geometry). Schedule = R8's proven rotation, re-derived:
// Units: A0..A3, B0..B3 = 64 rows x 64 cols = 1 gload_lds each (512 thr x 16B).
// Per tile: ph0 reads b1_(cp), stages B23(t+1)->np, MFMA q00;
//           ph1 reads a1_(cp), MFMA q01;
//           ph2 lgkm0+vmcnt(4)+bar, reads a0_(np), stages A0-3(t+2)->cp, MFMA q10;
//           ph3 vmcnt(4)+bar, reads b0_(np), stages B01(t+2)->cp, MFMA q11.
// Queue sim (per wave): ph2 wait: [A(t+1)4, B01(t+1)2, B23(t+1)2] -> vmcnt(4) drains
// A(t+1). ph3 wait: [B(t+1)4, A(t+2)4] -> vmcnt(4) drains B(t+1). Flights 3-4 phases.
// WAR: every staged region last-read >= lgkm0 + 2 barriers earlier (audited).
// Grid: 480 = GEMM1 384 (32bm x 12bn) + GEMM2 96 (8bm x 12bn, dispatched last to
// fill the second residency round; 480/512 = 93.75% fill, 1 block/CU).
__global__ __launch_bounds__(512, 1) void k_gemm256(
    const unsigned short* __restrict__ A1, const unsigned short* __restrict__ B1,
    const float* __restrict__ bias1, const float* __restrict__ g1,
    const float* __restrict__ ss1, unsigned short* __restrict__ C1,
    const unsigned short* __restrict__ A2, const unsigned short* __restrict__ B2,
    const float* __restrict__ bias2, const float* __restrict__ g2,
    const float* __restrict__ ss2, unsigned short* __restrict__ C2) {
  __shared__ __align__(16) unsigned short lA[2 * 4 * 4096];  // 64 KB: [buf][unit][64x64]
  __shared__ __align__(16) unsigned short lB[2 * 4 * 4096];  // 64 KB
  const int tid = threadIdx.x;
  const int wid = tid >> 6, lane = tid & 63;
  const int l15 = lane & 15, l4 = lane >> 4;
  const int wm = wid >> 2, wn = wid & 3;  // 2M x 4N waves
  const int rr8 = tid >> 3;               // unit row [0,64)
  const int scol8 = ((tid & 7) ^ (rr8 & 7)) << 3;  // pre-swizzled source col (rule 21)

  // bijective XCD swizzle over 480 blocks, then segment split
  int wg = (blockIdx.x & 7) * 60 + (blockIdx.x >> 3);
  const unsigned short* A;
  const unsigned short* B;
  const float* bias;
  const float* gptr;
  const float* ssptr;
  unsigned short* C;
  int K, nt, bm, bn;
  if (wg < 384) {
    bm = wg / 12; bn = wg % 12;
    A = A1; B = B1; bias = bias1; gptr = g1; ssptr = ss1; C = C1;
    K = 2048; nt = 32;
  } else {
    int w2 = wg - 384;
    bm = w2 / 12; bn = w2 % 12;
    A = A2; B = B2; bias = bias2; gptr = g2; ssptr = ss2; C = C2;
    K = 1024; nt = 16;
  }

  const unsigned short* Ab = A + (size_t)bm * 256 * K;
  const unsigned short* Bb = B + (size_t)bn * 256 * K;
  // per-lane 32-bit voffsets (base row/col within operand panel)
  const int voffA = rr8 * K + scol8;
  const int voffB = rr8 * K + scol8;

#define SB() __builtin_amdgcn_sched_barrier(0);

// unit U source rows: U*64 + rr8; dest: lX[buf][U][tid*8]
#define STAGE_AU(U, TS, BUFI)                                                      \
  {                                                                                \
    int ts_ = (TS) < nt ? (TS) : nt - 1;                                           \
    __builtin_amdgcn_global_load_lds(                                              \
        (gas_u32*)(Ab + (size_t)((U)*64) * K + ts_ * 64 + voffA),                  \
        (las_u32*)(lA + (BUFI)*16384 + (U)*4096 + tid * 8), 16, 0, 0);             \
  }
#define STAGE_BU(U, TS, BUFI)                                                      \
  {                                                                                \
    int ts_ = (TS) < nt ? (TS) : nt - 1;                                           \
    __builtin_amdgcn_global_load_lds(                                              \
        (gas_u32*)(Bb + (size_t)((U)*64) * K + ts_ * 64 + voffB),                  \
        (las_u32*)(lB + (BUFI)*16384 + (U)*4096 + tid * 8), 16, 0, 0);             \
  }

// A quadrant MQ rows: unit (wm*2+MQ), row-in-unit mi*16+l15
#define LDSA(DST, MQ, BUFI)                                                        \
  _Pragma("unroll") for (int mi = 0; mi < 4; ++mi) {                               \
    const unsigned short* ap =                                                     \
        lA + (BUFI)*16384 + (wm * 2 + (MQ)) * 4096 + (mi * 16 + l15) * 64;         \
    int s8 = l15 & 7;                                                              \
    DST[mi][0] = *(const bf16x8*)(ap + ((l4 ^ s8) << 3));                          \
    DST[mi][1] = *(const bf16x8*)(ap + (((4 | l4) ^ s8) << 3));                    \
  }

// B quadrant NQ rows: unit wn, row-in-unit NQ*32 + nj*16 + l15
#define LDSB(DST, NQ, BUFI)                                                        \
  _Pragma("unroll") for (int nj = 0; nj < 2; ++nj) {                               \
    const unsigned short* bp =                                                     \
        lB + (BUFI)*16384 + wn * 4096 + ((NQ)*32 + nj * 16 + l15) * 64;            \
    int s8 = l15 & 7;                                                              \
    DST[nj][0] = *(const bf16x8*)(bp + ((l4 ^ s8) << 3));                          \
    DST[nj][1] = *(const bf16x8*)(bp + (((4 | l4) ^ s8) << 3));                    \
  }

#define MFMAQ(MQ, NQ, AF, BF)                                                      \
  _Pragma("unroll") for (int ks = 0; ks < 2; ++ks)                                 \
  _Pragma("unroll") for (int mi = 0; mi < 4; ++mi)                                 \
  _Pragma("unroll") for (int nj = 0; nj < 2; ++nj)                                 \
    acc[(MQ)*4 + mi][(NQ)*2 + nj] = __builtin_amdgcn_mfma_f32_16x16x32_bf16(       \
        AF[mi][ks], BF[nj][ks], acc[(MQ)*4 + mi][(NQ)*2 + nj], 0, 0, 0);

// one K-tile; CP = buffer of tile t, NP = other buffer (literal after unroll-2)
#define TILE_BODY(T, CP, NP)                                                       \
  LDSB(b1_, 1, CP)                                                                 \
  STAGE_BU(2, (T) + 1, NP) STAGE_BU(3, (T) + 1, NP)                                \
  __builtin_amdgcn_s_setprio(1);                                                   \
  MFMAQ(0, 0, a0_, b0_)                                                            \
  __builtin_amdgcn_s_setprio(0);                                                   \
  LDSA(a1_, 1, CP)                                                                 \
  __builtin_amdgcn_s_setprio(1);                                                   \
  MFMAQ(0, 1, a0_, b1_)                                                            \
  __builtin_amdgcn_s_setprio(0);                                                   \
  asm volatile("s_waitcnt lgkmcnt(0)" ::: "memory");                               \
  asm volatile("s_waitcnt vmcnt(4)" ::: "memory");                                 \
  SB()                                                                             \
  __builtin_amdgcn_s_barrier();                                                    \
  LDSA(a0_, 0, NP)                                                                 \
  STAGE_AU(0, (T) + 2, CP) STAGE_AU(1, (T) + 2, CP)                                \
  STAGE_AU(2, (T) + 2, CP) STAGE_AU(3, (T) + 2, CP)                                \
  __builtin_amdgcn_s_setprio(1);                                                   \
  MFMAQ(1, 0, a1_, b0_)                                                            \
  __builtin_amdgcn_s_setprio(0);                                                   \
  asm volatile("s_waitcnt vmcnt(4)" ::: "memory");                                 \
  SB()                                                                             \
  __builtin_amdgcn_s_barrier();                                                    \
  LDSB(b0_, 0, NP)                                                                 \
  STAGE_BU(0, (T) + 2, CP) STAGE_BU(1, (T) + 2, CP)                                \
  __builtin_amdgcn_s_setprio(1);                                                   \
  MFMAQ(1, 1, a1_, b1_)                                                            \
  __builtin_amdgcn_s_setprio(0);

  f32x4 acc[8][4] = {};
  bf16x8 a0_[4][2], a1_[4][2], b0_[2][2], b1_[2][2];

  // ---- prologue: tile0 (8) + A0-3(1) (4) + B01(1) (2) = 14; drain tile0 -> vmcnt(6) --
  STAGE_AU(0, 0, 0) STAGE_AU(1, 0, 0) STAGE_AU(2, 0, 0) STAGE_AU(3, 0, 0)
  STAGE_BU(0, 0, 0) STAGE_BU(1, 0, 0) STAGE_BU(2, 0, 0) STAGE_BU(3, 0, 0)
  STAGE_AU(0, 1, 1) STAGE_AU(1, 1, 1) STAGE_AU(2, 1, 1) STAGE_AU(3, 1, 1)
  STAGE_BU(0, 1, 1) STAGE_BU(1, 1, 1)
  asm volatile("s_waitcnt vmcnt(6)" ::: "memory");
  SB()
  __builtin_amdgcn_s_barrier();
  LDSA(a0_, 0, 0)
  LDSB(b0_, 0, 0)

  for (int t = 0; t < nt; t += 2) {
    TILE_BODY(t, 0, 1)      // even tile: cp=0, np=1
    TILE_BODY(t + 1, 1, 0)  // odd tile:  cp=1, np=0
  }

  asm volatile("s_waitcnt vmcnt(0)" ::: "memory");

  const int N = 3072;
  float s = gptr[0] / sqrtf(ssptr[0]);
#pragma unroll
  for (int nq = 0; nq < 2; ++nq)
#pragma unroll
    for (int nj = 0; nj < 2; ++nj) {
      int gcol = bn * 256 + wn * 64 + nq * 32 + nj * 16 + l15;
      float bv = bias[gcol];
#pragma unroll
      for (int mq = 0; mq < 2; ++mq)
#pragma unroll
        for (int mi = 0; mi < 4; ++mi)
#pragma unroll
          for (int r = 0; r < 4; ++r) {
            int grow = bm * 256 + wm * 128 + mq * 64 + mi * 16 + l4 * 4 + r;
            float v = fmaxf(acc[mq * 4 + mi][nq * 2 + nj][r] * s + bv, 0.f);
            C[(size_t)grow * N + gcol] = f2bf(v);
          }
    }
#undef STAGE_AU
#undef STAGE_BU
#undef LDSA
#undef LDSB
#undef MFMAQ
#undef TILE_BODY
#undef SB
}

// -------- glimpse v5b: b-MAJOR block ids (4 blocks sharing V[b] -> same XCD L2) --------
__global__ __launch_bounds__(256, 2) void k_glimpse5(
    const unsigned short* __restrict__ Vh, const unsigned short* __restrict__ Qh,
    const float* __restrict__ hmat, const float* __restrict__ hbias,
    float* __restrict__ out) {
  __shared__ __align__(16) unsigned short lV[3][64 * 64];    // 24 KB
  __shared__ __align__(16) unsigned short lQ[2][4][32 * 64]; // 32 KB
  int tid = threadIdx.x;
  int wid = tid >> 6, lane = tid & 63;
  int l15 = lane & 15, l4 = lane >> 4;

  int id = blockIdx.x;
  int b = id >> 2, hv = id & 3;
  int h4 = hv & 1, vh = hv >> 1;  // heads h4*4..+3, V rows vh*64..+63

  const unsigned short* Vb = Vh + (size_t)b * 128 * 3072 + (size_t)vh * 64 * 3072;
  const unsigned short* Qb = Qh + (size_t)b * 32 * 3072;
  const float* hr0 = hmat + (h4 * 4 + 0) * 3072;
  const float* hr1 = hmat + (h4 * 4 + 1) * 3072;
  const float* hr2 = hmat + (h4 * 4 + 2) * 3072;
  const float* hr3 = hmat + (h4 * 4 + 3) * 3072;

  f32x4 acc[4][2] = {};
  const int rr8 = tid >> 3;
  const int ch8 = tid & 7;
  const int scol8 = (ch8 ^ (rr8 & 7)) << 3;
  const int qwoff = rr8 * 64 + scol8;
  const int qc = ch8 * 8;
  const int NT = 48;

#define VSTAGE(T, SLOT)                                                          \
  {                                                                              \
    int tc = (T) < NT ? (T) : NT - 1;                                            \
    _Pragma("unroll") for (int j = 0; j < 2; ++j) {                              \
      __builtin_amdgcn_global_load_lds(                                          \
          (gas_u32*)(Vb + (size_t)(j * 32 + rr8) * 3072 + tc * 64 + scol8),      \
          (las_u32*)(&lV[SLOT][0] + j * 2048 + tid * 8), 16, 0, 0);              \
    }                                                                            \
  }

#define QLOAD(T, RQ, H)                                                          \
  {                                                                              \
    int tc = (T) < NT ? (T) : NT - 1;                                            \
    RQ = *(const uint4*)(Qb + (size_t)rr8 * 3072 + tc * 64 + qc);                \
    H[0] = ((const float4*)(hr0 + tc * 64 + qc))[0];                             \
    H[1] = ((const float4*)(hr0 + tc * 64 + qc))[1];                             \
    H[2] = ((const float4*)(hr1 + tc * 64 + qc))[0];                             \
    H[3] = ((const float4*)(hr1 + tc * 64 + qc))[1];                             \
    H[4] = ((const float4*)(hr2 + tc * 64 + qc))[0];                             \
    H[5] = ((const float4*)(hr2 + tc * 64 + qc))[1];                             \
    H[6] = ((const float4*)(hr3 + tc * 64 + qc))[0];                             \
    H[7] = ((const float4*)(hr3 + tc * 64 + qc))[1];                             \
  }

#define QWRITE(CB, RQ, H)                                                        \
  {                                                                              \
    float e0 = bf2f((unsigned short)(RQ.x & 0xffff));                            \
    float e1 = bf2f((unsigned short)(RQ.x >> 16));                               \
    float e2 = bf2f((unsigned short)(RQ.y & 0xffff));                            \
    float e3 = bf2f((unsigned short)(RQ.y >> 16));                               \
    float e4 = bf2f((unsigned short)(RQ.z & 0xffff));                            \
    float e5 = bf2f((unsigned short)(RQ.z >> 16));                               \
    float e6 = bf2f((unsigned short)(RQ.w & 0xffff));                            \
    float e7 = bf2f((unsigned short)(RQ.w >> 16));                               \
    _Pragma("unroll") for (int hh = 0; hh < 4; ++hh) {                           \
      uint4 o;                                                                   \
      o.x = f2bf(e0 * H[hh * 2].x) | ((unsigned)f2bf(e1 * H[hh * 2].y) << 16);   \
      o.y = f2bf(e2 * H[hh * 2].z) | ((unsigned)f2bf(e3 * H[hh * 2].w) << 16);   \
      o.z = f2bf(e4 * H[hh * 2 + 1].x) |                                         \
            ((unsigned)f2bf(e5 * H[hh * 2 + 1].y) << 16);                        \
      o.w = f2bf(e6 * H[hh * 2 + 1].z) |                                         \
            ((unsigned)f2bf(e7 * H[hh * 2 + 1].w) << 16);                        \
      *(uint4*)(&lQ[CB][hh][0] + qwoff) = o;                                     \
    }                                                                            \
  }

#define GMFMA(SLOT, CB)                                                          \
  {                                                                              \
    int rlv = wid * 16 + l15;                                                    \
    int s8v = rlv & 7;                                                           \
    bf16x8 af[2];                                                                \
    af[0] = *(const bf16x8*)(&lV[SLOT][0] + rlv * 64 + ((l4 ^ s8v) << 3));       \
    af[1] = *(const bf16x8*)(&lV[SLOT][0] + rlv * 64 + (((4 | l4) ^ s8v) << 3)); \
    _Pragma("unroll") for (int hh = 0; hh < 4; ++hh) {                           \
      _Pragma("unroll") for (int nj = 0; nj < 2; ++nj) {                         \
        int rlq = nj * 16 + l15;                                                 \
        int s8q = rlq & 7;                                                       \
        bf16x8 bq0 = *(const bf16x8*)(&lQ[CB][hh][0] + rlq * 64 +                \
                                      ((l4 ^ s8q) << 3));                        \
        bf16x8 bq1 = *(const bf16x8*)(&lQ[CB][hh][0] + rlq * 64 +                \
                                      (((4 | l4) ^ s8q) << 3));                  \
        acc[hh][nj] =                                                            \
            __builtin_amdgcn_mfma_f32_16x16x32_bf16(af[0], bq0, acc[hh][nj], 0, 0, 0); \
        acc[hh][nj] =                                                            \
            __builtin_amdgcn_mfma_f32_16x16x32_bf16(af[1], bq1, acc[hh][nj], 0, 0, 0); \
      }                                                                          \
    }                                                                            \
  }

#define GBODY(T, CQ, CH, NQ, NH)                                                 \
  {                                                                              \
    QLOAD((T) + 2, NQ, NH)                                                       \
    asm volatile("s_waitcnt vmcnt(11)" ::: "memory");                            \
    asm volatile("s_waitcnt lgkmcnt(0)" ::: "memory");                           \
    __builtin_amdgcn_sched_barrier(0);                                           \
    __builtin_amdgcn_s_barrier();                                                \
    VSTAGE((T) + 2, ((T) + 2) % 3)                                               \
    QWRITE(((T) + 1) & 1, CQ, CH)                                                \
    GMFMA((T) % 3, (T) & 1)                                                      \
  }

  uint4 aq, bq_;
  float4 ah[8], bh[8];

  QLOAD(0, aq, ah)
  QLOAD(1, bq_, bh)
  VSTAGE(0, 0)
  VSTAGE(1, 1)
  asm volatile("s_waitcnt vmcnt(13)" ::: "memory");
  __builtin_amdgcn_sched_barrier(0);
  QWRITE(0, aq, ah)

  for (int t = 0; t < NT; t += 2) {
    GBODY(t, bq_, bh, aq, ah)
    GBODY(t + 1, aq, ah, bq_, bh)
  }
  asm volatile("s_waitcnt vmcnt(0) lgkmcnt(0)" ::: "memory");

#pragma unroll
  for (int hh = 0; hh < 4; ++hh) {
    int h = h4 * 4 + hh;
    float hb = hbias[h];
    float* ob = out + (size_t)(b * 8 + h) * 128 * 32;
#pragma unroll
    for (int nj = 0; nj < 2; ++nj)
#pragma unroll
      for (int r = 0; r < 4; ++r) {
        int row = vh * 64 + wid * 16 + l4 * 4 + r;
        int col = nj * 16 + l15;
        ob[row * 32 + col] = acc[hh][nj][r] + hb;
      }
  }
#undef VSTAGE
#undef QLOAD
#undef QWRITE
#undef GMFMA
#undef GBODY
}

extern "C" void kernel_launch(void* const* d_in, const int* in_sizes, int n_in,
                              void* d_out, int out_size, void* d_ws, size_t ws_size,
                              hipStream_t stream) {
  const float* v = (const float*)d_in[0];
  const float* q = (const float*)d_in[1];
  const float* v_w = (const float*)d_in[2];
  const float* v_g = (const float*)d_in[3];
  const float* v_b = (const float*)d_in[4];
  const float* q_w = (const float*)d_in[5];
  const float* q_g = (const float*)d_in[6];
  const float* q_b = (const float*)d_in[7];
  const float* hmat = (const float*)d_in[8];
  const float* hbias = (const float*)d_in[9];
  float* out = (float*)d_out;

  const size_t n_v = 16777216;   // 64*128*2048
  const size_t n_vw = 6291456;   // 3072*2048
  const size_t n_q = 2097152;    // 64*32*1024
  const size_t n_qw = 3145728;   // 3072*1024
  const size_t n_vh = 25165824;  // 8192*3072
  const size_t n_qh = 6291456;   // 2048*3072

  char* ws = (char*)d_ws;
  float* ss = (float*)ws;
  size_t off = 256;
  unsigned short* v_bf = (unsigned short*)(ws + off);  off += n_v * 2;
  unsigned short* vw_bf = (unsigned short*)(ws + off); off += n_vw * 2;
  unsigned short* q_bf = (unsigned short*)(ws + off);  off += n_q * 2;
  unsigned short* qw_bf = (unsigned short*)(ws + off); off += n_qw * 2;
  unsigned short* v_h = (unsigned short*)(ws + off);   off += n_vh * 2;
  unsigned short* q_h = (unsigned short*)(ws + off);   off += n_qh * 2;

  (void)hipMemsetAsync(ss, 0, 8, stream);
  k_prep<<<1536, 256, 0, stream>>>(v, q, v_w, q_w, v_bf, q_bf, vw_bf, qw_bf, ss);

  // merged GEMM1 (384 blocks, 256^2) + GEMM2 (96 blocks, 256^2) = 480 blocks
  k_gemm256<<<480, 512, 0, stream>>>(v_bf, vw_bf, v_b, v_g, ss + 0, v_h,
                                     q_bf, qw_bf, q_b, q_g, ss + 1, q_h);

  k_glimpse5<<<256, 256, 0, stream>>>(v_h, q_h, hmat, hbias, out);
}

// Round 11
// 198.043 us; speedup vs baseline: 1.1173x; 1.1173x over previous
//
#include <hip/hip_runtime.h>

typedef __attribute__((ext_vector_type(8))) __bf16 bf16x8;
typedef __attribute__((ext_vector_type(4))) float f32x4;
typedef const __attribute__((address_space(1))) unsigned int gas_u32;
typedef __attribute__((address_space(3))) unsigned int las_u32;

__device__ __forceinline__ unsigned short f2bf(float f) {
  unsigned u = __builtin_bit_cast(unsigned, f);
  u = (u + 0x7FFFu + ((u >> 16) & 1u)) >> 16;
  return (unsigned short)u;
}
__device__ __forceinline__ float bf2f(unsigned short h) {
  return __builtin_bit_cast(float, (unsigned)h << 16);
}

// ---------- merged prep: f32->bf16 converts (+ sum-of-squares for the two weights) ----
__global__ __launch_bounds__(256) void k_prep(
    const float* __restrict__ v, const float* __restrict__ q,
    const float* __restrict__ vw, const float* __restrict__ qw,
    unsigned short* __restrict__ v_bf, unsigned short* __restrict__ q_bf,
    unsigned short* __restrict__ vw_bf, unsigned short* __restrict__ qw_bf,
    float* __restrict__ ss) {
  __shared__ float red[4];
  int bid = blockIdx.x, tid = threadIdx.x;
  const float* in;
  unsigned short* out;
  float* ssout = nullptr;
  int n8, b0, nb;
  if (bid < 896) {
    in = v; out = v_bf; n8 = 2097152; b0 = bid; nb = 896;
  } else if (bid < 1008) {
    in = q; out = q_bf; n8 = 262144; b0 = bid - 896; nb = 112;
  } else if (bid < 1360) {
    in = vw; out = vw_bf; n8 = 786432; b0 = bid - 1008; nb = 352; ssout = ss + 0;
  } else {
    in = qw; out = qw_bf; n8 = 393216; b0 = bid - 1360; nb = 176; ssout = ss + 1;
  }
  float s = 0.f;
  for (int i = b0 * 256 + tid; i < n8; i += nb * 256) {
    float4 a = ((const float4*)in)[2 * i];
    float4 b = ((const float4*)in)[2 * i + 1];
    if (ssout) {
      s += a.x * a.x + a.y * a.y + a.z * a.z + a.w * a.w;
      s += b.x * b.x + b.y * b.y + b.z * b.z + b.w * b.w;
    }
    uint4 o;
    o.x = f2bf(a.x) | ((unsigned)f2bf(a.y) << 16);
    o.y = f2bf(a.z) | ((unsigned)f2bf(a.w) << 16);
    o.z = f2bf(b.x) | ((unsigned)f2bf(b.y) << 16);
    o.w = f2bf(b.z) | ((unsigned)f2bf(b.w) << 16);
    ((uint4*)out)[i] = o;
  }
  if (ssout) {
    for (int off = 32; off; off >>= 1) s += __shfl_down(s, off);
    if ((tid & 63) == 0) red[tid >> 6] = s;
    __syncthreads();
    if (tid == 0) atomicAdd(ssout, red[0] + red[1] + red[2] + red[3]);
  }
}

// ======== merged GEMM (R9 champion): 128x192 tile, 4 waves, rotation, 2 blocks/CU ====
// 2-D cache-tier XCD remap (R9). Schedule identical to R8/R9 (queue-sim verified).
// R11 change: epilogue reordered row-outer/nj-inner -> 192B contiguous writes per row
// per wave (R10 showed chunked same-line writes inflate WRITE_SIZE).
__global__ __launch_bounds__(256, 2) void k_gemm_cmb(
    const unsigned short* __restrict__ A1, const unsigned short* __restrict__ B1,
    const float* __restrict__ bias1, const float* __restrict__ g1,
    const float* __restrict__ ss1, unsigned short* __restrict__ C1,
    const unsigned short* __restrict__ A2, const unsigned short* __restrict__ B2,
    const float* __restrict__ bias2, const float* __restrict__ g2,
    const float* __restrict__ ss2, unsigned short* __restrict__ C2) {
  __shared__ __align__(16) unsigned short lA[2 * 128 * 64];  // 32 KB
  __shared__ __align__(16) unsigned short lB[2 * 192 * 64];  // 48 KB
  const int tid = threadIdx.x;
  const int wid = tid >> 6, lane = tid & 63;
  const int l15 = lane & 15, l4 = lane >> 4;
  const int wm = wid >> 1, wn = wid & 1;  // 2M x 2N waves
  const int rr8 = tid >> 3;
  const int scol8 = ((tid & 7) ^ (rr8 & 7)) << 3;  // pre-swizzled source col (rule 21)

  const unsigned short* A;
  const unsigned short* B;
  const float* bias;
  const float* gptr;
  const float* ssptr;
  unsigned short* C;
  int K, nt, bm, bn;
  if (blockIdx.x < 1024) {
    const int x = blockIdx.x & 7;      // XCD
    const int idx = blockIdx.x >> 3;   // [0,128) local
    const int bmHalf = idx >> 6;       // {0,1}
    const int rem = idx & 63;
    const int bn_l = rem >> 4;                  // [0,4)
    const int bm_l = bmHalf * 16 + (rem & 15);  // [0,32)
    bm = (x >> 2) * 32 + bm_l;         // [0,64)
    bn = (x & 3) * 4 + bn_l;           // [0,16)
    A = A1; B = B1; bias = bias1; gptr = g1; ssptr = ss1; C = C1;
    K = 2048; nt = 32;
  } else {
    const int bid = blockIdx.x - 1024;
    const int x = blockIdx.x & 7;
    const int idx = bid >> 3;          // [0,32)
    const int bm_l = idx & 7, bn_l = idx >> 3;  // [0,8),[0,4)
    bm = (x >> 2) * 8 + bm_l;          // [0,16)
    bn = (x & 3) * 4 + bn_l;           // [0,16)
    A = A2; B = B2; bias = bias2; gptr = g2; ssptr = ss2; C = C2;
    K = 1024; nt = 16;
  }

  const unsigned short* Ab = A + (size_t)bm * 128 * K;
  const unsigned short* Bb = B + (size_t)bn * 192 * K;

  // hoisted per-lane staging source pointers (unit U, half j)
  const unsigned short* sA00 = Ab + (size_t)(rr8) * K + scol8;
  const unsigned short* sA01 = Ab + (size_t)(32 + rr8) * K + scol8;
  const unsigned short* sA10 = Ab + (size_t)(64 + rr8) * K + scol8;
  const unsigned short* sA11 = Ab + (size_t)(96 + rr8) * K + scol8;
  const unsigned short* sB00 = Bb + (size_t)(rr8) * K + scol8;
  const unsigned short* sB01 = Bb + (size_t)(32 + rr8) * K + scol8;
  const unsigned short* sB10 = Bb + (size_t)(64 + rr8) * K + scol8;
  const unsigned short* sB11 = Bb + (size_t)(96 + rr8) * K + scol8;
  const unsigned short* sB20 = Bb + (size_t)(128 + rr8) * K + scol8;
  const unsigned short* sB21 = Bb + (size_t)(160 + rr8) * K + scol8;

#define SB() __builtin_amdgcn_sched_barrier(0);

#define STAGE_A(U, TS, BUFI)                                                       \
  {                                                                                \
    int ts_ = (TS) < nt ? (TS) : nt - 1;                                           \
    __builtin_amdgcn_global_load_lds(                                              \
        (gas_u32*)(sA##U##0 + (size_t)ts_ * 64),                                   \
        (las_u32*)(lA + (BUFI)*8192 + (U)*4096 + tid * 8), 16, 0, 0);              \
    __builtin_amdgcn_global_load_lds(                                              \
        (gas_u32*)(sA##U##1 + (size_t)ts_ * 64),                                   \
        (las_u32*)(lA + (BUFI)*8192 + (U)*4096 + 2048 + tid * 8), 16, 0, 0);       \
  }

#define STAGE_B(U, TS, BUFI)                                                       \
  {                                                                                \
    int ts_ = (TS) < nt ? (TS) : nt - 1;                                           \
    __builtin_amdgcn_global_load_lds(                                              \
        (gas_u32*)(sB##U##0 + (size_t)ts_ * 64),                                   \
        (las_u32*)(lB + (BUFI)*12288 + (U)*4096 + tid * 8), 16, 0, 0);             \
    __builtin_amdgcn_global_load_lds(                                              \
        (gas_u32*)(sB##U##1 + (size_t)ts_ * 64),                                   \
        (las_u32*)(lB + (BUFI)*12288 + (U)*4096 + 2048 + tid * 8), 16, 0, 0);      \
  }

#define LDSA(DST, MQ, TP)                                                          \
  _Pragma("unroll") for (int i2 = 0; i2 < 2; ++i2) {                               \
    int rl = wm * 64 + ((MQ)*2 + i2) * 16 + l15;                                   \
    const unsigned short* ap = lA + (TP)*8192 + rl * 64;                           \
    int s8 = rl & 7;                                                               \
    DST[i2][0] = *(const bf16x8*)(ap + ((l4 ^ s8) << 3));                          \
    DST[i2][1] = *(const bf16x8*)(ap + (((4 | l4) ^ s8) << 3));                    \
  }

#define LDSB(DST, NQ, TP)                                                          \
  _Pragma("unroll") for (int j3 = 0; j3 < 3; ++j3) {                               \
    int rl = wn * 96 + ((NQ)*3 + j3) * 16 + l15;                                   \
    const unsigned short* bp = lB + (TP)*12288 + rl * 64;                          \
    int s8 = rl & 7;                                                               \
    DST[j3][0] = *(const bf16x8*)(bp + ((l4 ^ s8) << 3));                          \
    DST[j3][1] = *(const bf16x8*)(bp + (((4 | l4) ^ s8) << 3));                    \
  }

#define MFMA12(MQ, NQ, AF, BF)                                                     \
  _Pragma("unroll") for (int ks = 0; ks < 2; ++ks)                                 \
  _Pragma("unroll") for (int i2 = 0; i2 < 2; ++i2)                                 \
  _Pragma("unroll") for (int j3 = 0; j3 < 3; ++j3)                                 \
    acc[(MQ)*2 + i2][(NQ)*3 + j3] = __builtin_amdgcn_mfma_f32_16x16x32_bf16(       \
        AF[i2][ks], BF[j3][ks], acc[(MQ)*2 + i2][(NQ)*3 + j3], 0, 0, 0);

#define TILE_BODY(T, CP, NP)                                                       \
  LDSB(b1_, 1, CP)                                                                 \
  STAGE_B(2, (T) + 1, NP)                                                          \
  __builtin_amdgcn_s_setprio(1);                                                   \
  MFMA12(0, 0, a0_, b0_)                                                           \
  __builtin_amdgcn_s_setprio(0);                                                   \
  LDSA(a1_, 1, CP)                                                                 \
  __builtin_amdgcn_s_setprio(1);                                                   \
  MFMA12(0, 1, a0_, b1_)                                                           \
  __builtin_amdgcn_s_setprio(0);                                                   \
  asm volatile("s_waitcnt lgkmcnt(0)" ::: "memory");                               \
  asm volatile("s_waitcnt vmcnt(6)" ::: "memory");                                 \
  SB()                                                                             \
  __builtin_amdgcn_s_barrier();                                                    \
  LDSA(a0_, 0, NP)                                                                 \
  STAGE_A(0, (T) + 2, CP) STAGE_A(1, (T) + 2, CP)                                  \
  __builtin_amdgcn_s_setprio(1);                                                   \
  MFMA12(1, 0, a1_, b0_)                                                           \
  __builtin_amdgcn_s_setprio(0);                                                   \
  asm volatile("s_waitcnt vmcnt(4)" ::: "memory");                                 \
  SB()                                                                             \
  __builtin_amdgcn_s_barrier();                                                    \
  LDSB(b0_, 0, NP)                                                                 \
  STAGE_B(0, (T) + 2, CP) STAGE_B(1, (T) + 2, CP)                                  \
  __builtin_amdgcn_s_setprio(1);                                                   \
  MFMA12(1, 1, a1_, b1_)                                                           \
  __builtin_amdgcn_s_setprio(0);

  f32x4 acc[4][6] = {};
  bf16x8 a0_[2][2], a1_[2][2], b0_[3][2], b1_[3][2];

  STAGE_A(0, 0, 0) STAGE_A(1, 0, 0) STAGE_B(0, 0, 0) STAGE_B(1, 0, 0) STAGE_B(2, 0, 0)
  STAGE_A(0, 1, 1) STAGE_A(1, 1, 1)
  asm volatile("s_waitcnt vmcnt(4)" ::: "memory");
  SB()
  __builtin_amdgcn_s_barrier();
  LDSA(a0_, 0, 0)
  STAGE_B(0, 1, 1) STAGE_B(1, 1, 1)
  LDSB(b0_, 0, 0)

  for (int t = 0; t < nt; t += 2) {
    TILE_BODY(t, 0, 1)
    TILE_BODY(t + 1, 1, 0)
  }

  asm volatile("s_waitcnt vmcnt(0)" ::: "memory");

  const int N = 3072;
  float s = gptr[0] / sqrtf(ssptr[0]);
  float bv[6];
#pragma unroll
  for (int nj = 0; nj < 6; ++nj) bv[nj] = bias[bn * 192 + wn * 96 + nj * 16 + l15];
#pragma unroll
  for (int mi = 0; mi < 4; ++mi) {
#pragma unroll
    for (int r = 0; r < 4; ++r) {
      int grow = bm * 128 + wm * 64 + mi * 16 + l4 * 4 + r;
      size_t rowoff = (size_t)grow * N;
#pragma unroll
      for (int nj = 0; nj < 6; ++nj) {
        int gcol = bn * 192 + wn * 96 + nj * 16 + l15;
        float v = fmaxf(acc[mi][nj][r] * s + bv[nj], 0.f);
        C[rowoff + gcol] = f2bf(v);
      }
    }
  }
#undef STAGE_A
#undef STAGE_B
#undef LDSA
#undef LDSB
#undef MFMA12
#undef TILE_BODY
#undef SB
}

// -------- glimpse v6: 2 heads/block, 512 blocks, 4 blocks/CU (40KB LDS) --------
// block id = b*8 + hv; h2 = hv>>1 (heads h2, h2+4), vh = hv&1 (V-row half).
// Mechanism: 4 barrier domains x 16 waves per CU hide the per-iter barrier/vmem
// latency that capped v5 (2 blocks/8 waves). b-major ids keep V[b]/Q[b] L2-shared.
// vmcnt queue sim: per iter QLOAD=5 (Q uint4 + 4 hm float4), VSTAGE=2.
// Prologue: [Q0(5) Q1(5) V0(2) V1(2)]=14 -> vmcnt(9) drains Q0.
// Iter T wait: [V(T)2, Q(T+1)5, V(T+1)2, Q(T+2)5]=14 -> vmcnt(7) drains V(T)+Q(T+1).
__global__ __launch_bounds__(256, 4) void k_glimpse6(
    const unsigned short* __restrict__ Vh, const unsigned short* __restrict__ Qh,
    const float* __restrict__ hmat, const float* __restrict__ hbias,
    float* __restrict__ out) {
  __shared__ __align__(16) unsigned short lV[3][64 * 64];    // 24 KB
  __shared__ __align__(16) unsigned short lQ[2][2][32 * 64]; // 16 KB
  int tid = threadIdx.x;
  int wid = tid >> 6, lane = tid & 63;
  int l15 = lane & 15, l4 = lane >> 4;

  int id = blockIdx.x;
  int b = id >> 3, hv = id & 7;
  int h2 = hv >> 1, vh = hv & 1;  // heads h2, h2+4; V rows vh*64..+63

  const unsigned short* Vb = Vh + (size_t)b * 128 * 3072 + (size_t)vh * 64 * 3072;
  const unsigned short* Qb = Qh + (size_t)b * 32 * 3072;
  const float* hr0 = hmat + h2 * 3072;
  const float* hr1 = hmat + (h2 + 4) * 3072;

  f32x4 acc[2][2] = {};
  const int rr8 = tid >> 3;
  const int ch8 = tid & 7;
  const int scol8 = (ch8 ^ (rr8 & 7)) << 3;
  const int qwoff = rr8 * 64 + scol8;
  const int qc = ch8 * 8;
  const int NT = 48;

#define VSTAGE(T, SLOT)                                                          \
  {                                                                              \
    int tc = (T) < NT ? (T) : NT - 1;                                            \
    _Pragma("unroll") for (int j = 0; j < 2; ++j) {                              \
      __builtin_amdgcn_global_load_lds(                                          \
          (gas_u32*)(Vb + (size_t)(j * 32 + rr8) * 3072 + tc * 64 + scol8),      \
          (las_u32*)(&lV[SLOT][0] + j * 2048 + tid * 8), 16, 0, 0);              \
    }                                                                            \
  }

  // 5 vmem loads: Q uint4 + 2 hm rows x 2 float4
#define QLOAD(T, RQ, H)                                                          \
  {                                                                              \
    int tc = (T) < NT ? (T) : NT - 1;                                            \
    RQ = *(const uint4*)(Qb + (size_t)rr8 * 3072 + tc * 64 + qc);                \
    H[0] = ((const float4*)(hr0 + tc * 64 + qc))[0];                             \
    H[1] = ((const float4*)(hr0 + tc * 64 + qc))[1];                             \
    H[2] = ((const float4*)(hr1 + tc * 64 + qc))[0];                             \
    H[3] = ((const float4*)(hr1 + tc * 64 + qc))[1];                             \
  }

#define QWRITE(CB, RQ, H)                                                        \
  {                                                                              \
    float e0 = bf2f((unsigned short)(RQ.x & 0xffff));                            \
    float e1 = bf2f((unsigned short)(RQ.x >> 16));                               \
    float e2 = bf2f((unsigned short)(RQ.y & 0xffff));                            \
    float e3 = bf2f((unsigned short)(RQ.y >> 16));                               \
    float e4 = bf2f((unsigned short)(RQ.z & 0xffff));                            \
    float e5 = bf2f((unsigned short)(RQ.z >> 16));                               \
    float e6 = bf2f((unsigned short)(RQ.w & 0xffff));                            \
    float e7 = bf2f((unsigned short)(RQ.w >> 16));                               \
    _Pragma("unroll") for (int hh = 0; hh < 2; ++hh) {                           \
      uint4 o;                                                                   \
      o.x = f2bf(e0 * H[hh * 2].x) | ((unsigned)f2bf(e1 * H[hh * 2].y) << 16);   \
      o.y = f2bf(e2 * H[hh * 2].z) | ((unsigned)f2bf(e3 * H[hh * 2].w) << 16);   \
      o.z = f2bf(e4 * H[hh * 2 + 1].x) |                                         \
            ((unsigned)f2bf(e5 * H[hh * 2 + 1].y) << 16);                        \
      o.w = f2bf(e6 * H[hh * 2 + 1].z) |                                         \
            ((unsigned)f2bf(e7 * H[hh * 2 + 1].w) << 16);                        \
      *(uint4*)(&lQ[CB][hh][0] + qwoff) = o;                                     \
    }                                                                            \
  }

#define GMFMA(SLOT, CB)                                                          \
  {                                                                              \
    int rlv = wid * 16 + l15;                                                    \
    int s8v = rlv & 7;                                                           \
    bf16x8 af0 = *(const bf16x8*)(&lV[SLOT][0] + rlv * 64 + ((l4 ^ s8v) << 3));  \
    bf16x8 af1 =                                                                 \
        *(const bf16x8*)(&lV[SLOT][0] + rlv * 64 + (((4 | l4) ^ s8v) << 3));     \
    _Pragma("unroll") for (int hh = 0; hh < 2; ++hh) {                           \
      _Pragma("unroll") for (int nj = 0; nj < 2; ++nj) {                         \
        int rlq = nj * 16 + l15;                                                 \
        int s8q = rlq & 7;                                                       \
        bf16x8 bq0 = *(const bf16x8*)(&lQ[CB][hh][0] + rlq * 64 +                \
                                      ((l4 ^ s8q) << 3));                        \
        bf16x8 bq1 = *(const bf16x8*)(&lQ[CB][hh][0] + rlq * 64 +                \
                                      (((4 | l4) ^ s8q) << 3));                  \
        acc[hh][nj] =                                                            \
            __builtin_amdgcn_mfma_f32_16x16x32_bf16(af0, bq0, acc[hh][nj], 0, 0, 0); \
        acc[hh][nj] =                                                            \
            __builtin_amdgcn_mfma_f32_16x16x32_bf16(af1, bq1, acc[hh][nj], 0, 0, 0); \
      }                                                                          \
    }                                                                            \
  }

#define GBODY(T, CQ, CH, NQ, NH)                                                 \
  {                                                                              \
    QLOAD((T) + 2, NQ, NH)                                                       \
    asm volatile("s_waitcnt vmcnt(7)" ::: "memory");                             \
    asm volatile("s_waitcnt lgkmcnt(0)" ::: "memory");                           \
    __builtin_amdgcn_sched_barrier(0);                                           \
    __builtin_amdgcn_s_barrier();                                                \
    VSTAGE((T) + 2, ((T) + 2) % 3)                                               \
    QWRITE(((T) + 1) & 1, CQ, CH)                                                \
    GMFMA((T) % 3, (T) & 1)                                                      \
  }

  uint4 aq, bq_;
  float4 ah[4], bh[4];

  QLOAD(0, aq, ah)
  QLOAD(1, bq_, bh)
  VSTAGE(0, 0)
  VSTAGE(1, 1)
  asm volatile("s_waitcnt vmcnt(9)" ::: "memory");
  __builtin_amdgcn_sched_barrier(0);
  QWRITE(0, aq, ah)

  for (int t = 0; t < NT; t += 2) {
    GBODY(t, bq_, bh, aq, ah)
    GBODY(t + 1, aq, ah, bq_, bh)
  }
  asm volatile("s_waitcnt vmcnt(0) lgkmcnt(0)" ::: "memory");

#pragma unroll
  for (int hh = 0; hh < 2; ++hh) {
    int h = h2 + hh * 4;
    float hb = hbias[h];
    float* ob = out + (size_t)(b * 8 + h) * 128 * 32;
#pragma unroll
    for (int nj = 0; nj < 2; ++nj)
#pragma unroll
      for (int r = 0; r < 4; ++r) {
        int row = vh * 64 + wid * 16 + l4 * 4 + r;
        int col = nj * 16 + l15;
        ob[row * 32 + col] = acc[hh][nj][r] + hb;
      }
  }
#undef VSTAGE
#undef QLOAD
#undef QWRITE
#undef GMFMA
#undef GBODY
}

extern "C" void kernel_launch(void* const* d_in, const int* in_sizes, int n_in,
                              void* d_out, int out_size, void* d_ws, size_t ws_size,
                              hipStream_t stream) {
  const float* v = (const float*)d_in[0];
  const float* q = (const float*)d_in[1];
  const float* v_w = (const float*)d_in[2];
  const float* v_g = (const float*)d_in[3];
  const float* v_b = (const float*)d_in[4];
  const float* q_w = (const float*)d_in[5];
  const float* q_g = (const float*)d_in[6];
  const float* q_b = (const float*)d_in[7];
  const float* hmat = (const float*)d_in[8];
  const float* hbias = (const float*)d_in[9];
  float* out = (float*)d_out;

  const size_t n_v = 16777216;   // 64*128*2048
  const size_t n_vw = 6291456;   // 3072*2048
  const size_t n_q = 2097152;    // 64*32*1024
  const size_t n_qw = 3145728;   // 3072*1024
  const size_t n_vh = 25165824;  // 8192*3072
  const size_t n_qh = 6291456;   // 2048*3072

  char* ws = (char*)d_ws;
  float* ss = (float*)ws;
  size_t off = 256;
  unsigned short* v_bf = (unsigned short*)(ws + off);  off += n_v * 2;
  unsigned short* vw_bf = (unsigned short*)(ws + off); off += n_vw * 2;
  unsigned short* q_bf = (unsigned short*)(ws + off);  off += n_q * 2;
  unsigned short* qw_bf = (unsigned short*)(ws + off); off += n_qw * 2;
  unsigned short* v_h = (unsigned short*)(ws + off);   off += n_vh * 2;
  unsigned short* q_h = (unsigned short*)(ws + off);   off += n_qh * 2;

  (void)hipMemsetAsync(ss, 0, 8, stream);
  k_prep<<<1536, 256, 0, stream>>>(v, q, v_w, q_w, v_bf, q_bf, vw_bf, qw_bf, ss);

  // merged GEMM1 (1024 blocks) + GEMM2 (256 blocks), cache-tier XCD remap (R9)
  k_gemm_cmb<<<1280, 256, 0, stream>>>(v_bf, vw_bf, v_b, v_g, ss + 0, v_h,
                                       q_bf, qw_bf, q_b, q_g, ss + 1, q_h);

  k_glimpse6<<<512, 256, 0, stream>>>(v_h, q_h, hmat, hbias, out);
}

// Round 12
// 191.003 us; speedup vs baseline: 1.1585x; 1.0369x over previous
//
#include <hip/hip_runtime.h>

typedef __attribute__((ext_vector_type(8))) __bf16 bf16x8;
typedef __attribute__((ext_vector_type(4))) float f32x4;
typedef const __attribute__((address_space(1))) unsigned int gas_u32;
typedef __attribute__((address_space(3))) unsigned int las_u32;

__device__ __forceinline__ unsigned short f2bf(float f) {
  unsigned u = __builtin_bit_cast(unsigned, f);
  u = (u + 0x7FFFu + ((u >> 16) & 1u)) >> 16;
  return (unsigned short)u;
}
__device__ __forceinline__ float bf2f(unsigned short h) {
  return __builtin_bit_cast(float, (unsigned)h << 16);
}

// ---------- merged prep: f32->bf16 converts (+ sum-of-squares for the two weights) ----
__global__ __launch_bounds__(256) void k_prep(
    const float* __restrict__ v, const float* __restrict__ q,
    const float* __restrict__ vw, const float* __restrict__ qw,
    unsigned short* __restrict__ v_bf, unsigned short* __restrict__ q_bf,
    unsigned short* __restrict__ vw_bf, unsigned short* __restrict__ qw_bf,
    float* __restrict__ ss) {
  __shared__ float red[4];
  int bid = blockIdx.x, tid = threadIdx.x;
  const float* in;
  unsigned short* out;
  float* ssout = nullptr;
  int n8, b0, nb;
  if (bid < 896) {
    in = v; out = v_bf; n8 = 2097152; b0 = bid; nb = 896;
  } else if (bid < 1008) {
    in = q; out = q_bf; n8 = 262144; b0 = bid - 896; nb = 112;
  } else if (bid < 1360) {
    in = vw; out = vw_bf; n8 = 786432; b0 = bid - 1008; nb = 352; ssout = ss + 0;
  } else {
    in = qw; out = qw_bf; n8 = 393216; b0 = bid - 1360; nb = 176; ssout = ss + 1;
  }
  float s = 0.f;
  for (int i = b0 * 256 + tid; i < n8; i += nb * 256) {
    float4 a = ((const float4*)in)[2 * i];
    float4 b = ((const float4*)in)[2 * i + 1];
    if (ssout) {
      s += a.x * a.x + a.y * a.y + a.z * a.z + a.w * a.w;
      s += b.x * b.x + b.y * b.y + b.z * b.z + b.w * b.w;
    }
    uint4 o;
    o.x = f2bf(a.x) | ((unsigned)f2bf(a.y) << 16);
    o.y = f2bf(a.z) | ((unsigned)f2bf(a.w) << 16);
    o.z = f2bf(b.x) | ((unsigned)f2bf(b.y) << 16);
    o.w = f2bf(b.z) | ((unsigned)f2bf(b.w) << 16);
    ((uint4*)out)[i] = o;
  }
  if (ssout) {
    for (int off = 32; off; off >>= 1) s += __shfl_down(s, off);
    if ((tid & 63) == 0) red[tid >> 6] = s;
    __syncthreads();
    if (tid == 0) atomicAdd(ssout, red[0] + red[1] + red[2] + red[3]);
  }
}

// ======== merged GEMM (champion, frozen): 128x192 tile, 4 waves, rotation, 2 blk/CU ==
// Model closed (R12): MFMA demand 1862cy/tile/CU vs LDS-port 1900-2240cy -> both pipes
// near-saturated; wall 2155cy is within 14% of max(matrix,port). Further gains need
// bigger wave tiles (registers > 256/wave) = different design family. FROZEN.
__global__ __launch_bounds__(256, 2) void k_gemm_cmb(
    const unsigned short* __restrict__ A1, const unsigned short* __restrict__ B1,
    const float* __restrict__ bias1, const float* __restrict__ g1,
    const float* __restrict__ ss1, unsigned short* __restrict__ C1,
    const unsigned short* __restrict__ A2, const unsigned short* __restrict__ B2,
    const float* __restrict__ bias2, const float* __restrict__ g2,
    const float* __restrict__ ss2, unsigned short* __restrict__ C2) {
  __shared__ __align__(16) unsigned short lA[2 * 128 * 64];  // 32 KB
  __shared__ __align__(16) unsigned short lB[2 * 192 * 64];  // 48 KB
  const int tid = threadIdx.x;
  const int wid = tid >> 6, lane = tid & 63;
  const int l15 = lane & 15, l4 = lane >> 4;
  const int wm = wid >> 1, wn = wid & 1;  // 2M x 2N waves
  const int rr8 = tid >> 3;
  const int scol8 = ((tid & 7) ^ (rr8 & 7)) << 3;  // pre-swizzled source col (rule 21)

  const unsigned short* A;
  const unsigned short* B;
  const float* bias;
  const float* gptr;
  const float* ssptr;
  unsigned short* C;
  int K, nt, bm, bn;
  if (blockIdx.x < 1024) {
    const int x = blockIdx.x & 7;      // XCD
    const int idx = blockIdx.x >> 3;   // [0,128) local
    const int bmHalf = idx >> 6;       // {0,1}
    const int rem = idx & 63;
    const int bn_l = rem >> 4;                  // [0,4)
    const int bm_l = bmHalf * 16 + (rem & 15);  // [0,32)
    bm = (x >> 2) * 32 + bm_l;         // [0,64)
    bn = (x & 3) * 4 + bn_l;           // [0,16)
    A = A1; B = B1; bias = bias1; gptr = g1; ssptr = ss1; C = C1;
    K = 2048; nt = 32;
  } else {
    const int bid = blockIdx.x - 1024;
    const int x = blockIdx.x & 7;
    const int idx = bid >> 3;          // [0,32)
    const int bm_l = idx & 7, bn_l = idx >> 3;  // [0,8),[0,4)
    bm = (x >> 2) * 8 + bm_l;          // [0,16)
    bn = (x & 3) * 4 + bn_l;           // [0,16)
    A = A2; B = B2; bias = bias2; gptr = g2; ssptr = ss2; C = C2;
    K = 1024; nt = 16;
  }

  const unsigned short* Ab = A + (size_t)bm * 128 * K;
  const unsigned short* Bb = B + (size_t)bn * 192 * K;

  const unsigned short* sA00 = Ab + (size_t)(rr8) * K + scol8;
  const unsigned short* sA01 = Ab + (size_t)(32 + rr8) * K + scol8;
  const unsigned short* sA10 = Ab + (size_t)(64 + rr8) * K + scol8;
  const unsigned short* sA11 = Ab + (size_t)(96 + rr8) * K + scol8;
  const unsigned short* sB00 = Bb + (size_t)(rr8) * K + scol8;
  const unsigned short* sB01 = Bb + (size_t)(32 + rr8) * K + scol8;
  const unsigned short* sB10 = Bb + (size_t)(64 + rr8) * K + scol8;
  const unsigned short* sB11 = Bb + (size_t)(96 + rr8) * K + scol8;
  const unsigned short* sB20 = Bb + (size_t)(128 + rr8) * K + scol8;
  const unsigned short* sB21 = Bb + (size_t)(160 + rr8) * K + scol8;

#define SB() __builtin_amdgcn_sched_barrier(0);

#define STAGE_A(U, TS, BUFI)                                                       \
  {                                                                                \
    int ts_ = (TS) < nt ? (TS) : nt - 1;                                           \
    __builtin_amdgcn_global_load_lds(                                              \
        (gas_u32*)(sA##U##0 + (size_t)ts_ * 64),                                   \
        (las_u32*)(lA + (BUFI)*8192 + (U)*4096 + tid * 8), 16, 0, 0);              \
    __builtin_amdgcn_global_load_lds(                                              \
        (gas_u32*)(sA##U##1 + (size_t)ts_ * 64),                                   \
        (las_u32*)(lA + (BUFI)*8192 + (U)*4096 + 2048 + tid * 8), 16, 0, 0);       \
  }

#define STAGE_B(U, TS, BUFI)                                                       \
  {                                                                                \
    int ts_ = (TS) < nt ? (TS) : nt - 1;                                           \
    __builtin_amdgcn_global_load_lds(                                              \
        (gas_u32*)(sB##U##0 + (size_t)ts_ * 64),                                   \
        (las_u32*)(lB + (BUFI)*12288 + (U)*4096 + tid * 8), 16, 0, 0);             \
    __builtin_amdgcn_global_load_lds(                                              \
        (gas_u32*)(sB##U##1 + (size_t)ts_ * 64),                                   \
        (las_u32*)(lB + (BUFI)*12288 + (U)*4096 + 2048 + tid * 8), 16, 0, 0);      \
  }

#define LDSA(DST, MQ, TP)                                                          \
  _Pragma("unroll") for (int i2 = 0; i2 < 2; ++i2) {                               \
    int rl = wm * 64 + ((MQ)*2 + i2) * 16 + l15;                                   \
    const unsigned short* ap = lA + (TP)*8192 + rl * 64;                           \
    int s8 = rl & 7;                                                               \
    DST[i2][0] = *(const bf16x8*)(ap + ((l4 ^ s8) << 3));                          \
    DST[i2][1] = *(const bf16x8*)(ap + (((4 | l4) ^ s8) << 3));                    \
  }

#define LDSB(DST, NQ, TP)                                                          \
  _Pragma("unroll") for (int j3 = 0; j3 < 3; ++j3) {                               \
    int rl = wn * 96 + ((NQ)*3 + j3) * 16 + l15;                                   \
    const unsigned short* bp = lB + (TP)*12288 + rl * 64;                          \
    int s8 = rl & 7;                                                               \
    DST[j3][0] = *(const bf16x8*)(bp + ((l4 ^ s8) << 3));                          \
    DST[j3][1] = *(const bf16x8*)(bp + (((4 | l4) ^ s8) << 3));                    \
  }

#define MFMA12(MQ, NQ, AF, BF)                                                     \
  _Pragma("unroll") for (int ks = 0; ks < 2; ++ks)                                 \
  _Pragma("unroll") for (int i2 = 0; i2 < 2; ++i2)                                 \
  _Pragma("unroll") for (int j3 = 0; j3 < 3; ++j3)                                 \
    acc[(MQ)*2 + i2][(NQ)*3 + j3] = __builtin_amdgcn_mfma_f32_16x16x32_bf16(       \
        AF[i2][ks], BF[j3][ks], acc[(MQ)*2 + i2][(NQ)*3 + j3], 0, 0, 0);

#define TILE_BODY(T, CP, NP)                                                       \
  LDSB(b1_, 1, CP)                                                                 \
  STAGE_B(2, (T) + 1, NP)                                                          \
  __builtin_amdgcn_s_setprio(1);                                                   \
  MFMA12(0, 0, a0_, b0_)                                                           \
  __builtin_amdgcn_s_setprio(0);                                                   \
  LDSA(a1_, 1, CP)                                                                 \
  __builtin_amdgcn_s_setprio(1);                                                   \
  MFMA12(0, 1, a0_, b1_)                                                           \
  __builtin_amdgcn_s_setprio(0);                                                   \
  asm volatile("s_waitcnt lgkmcnt(0)" ::: "memory");                               \
  asm volatile("s_waitcnt vmcnt(6)" ::: "memory");                                 \
  SB()                                                                             \
  __builtin_amdgcn_s_barrier();                                                    \
  LDSA(a0_, 0, NP)                                                                 \
  STAGE_A(0, (T) + 2, CP) STAGE_A(1, (T) + 2, CP)                                  \
  __builtin_amdgcn_s_setprio(1);                                                   \
  MFMA12(1, 0, a1_, b0_)                                                           \
  __builtin_amdgcn_s_setprio(0);                                                   \
  asm volatile("s_waitcnt vmcnt(4)" ::: "memory");                                 \
  SB()                                                                             \
  __builtin_amdgcn_s_barrier();                                                    \
  LDSB(b0_, 0, NP)                                                                 \
  STAGE_B(0, (T) + 2, CP) STAGE_B(1, (T) + 2, CP)                                  \
  __builtin_amdgcn_s_setprio(1);                                                   \
  MFMA12(1, 1, a1_, b1_)                                                           \
  __builtin_amdgcn_s_setprio(0);

  f32x4 acc[4][6] = {};
  bf16x8 a0_[2][2], a1_[2][2], b0_[3][2], b1_[3][2];

  STAGE_A(0, 0, 0) STAGE_A(1, 0, 0) STAGE_B(0, 0, 0) STAGE_B(1, 0, 0) STAGE_B(2, 0, 0)
  STAGE_A(0, 1, 1) STAGE_A(1, 1, 1)
  asm volatile("s_waitcnt vmcnt(4)" ::: "memory");
  SB()
  __builtin_amdgcn_s_barrier();
  LDSA(a0_, 0, 0)
  STAGE_B(0, 1, 1) STAGE_B(1, 1, 1)
  LDSB(b0_, 0, 0)

  for (int t = 0; t < nt; t += 2) {
    TILE_BODY(t, 0, 1)
    TILE_BODY(t + 1, 1, 0)
  }

  asm volatile("s_waitcnt vmcnt(0)" ::: "memory");

  const int N = 3072;
  float s = gptr[0] / sqrtf(ssptr[0]);
  float bv[6];
#pragma unroll
  for (int nj = 0; nj < 6; ++nj) bv[nj] = bias[bn * 192 + wn * 96 + nj * 16 + l15];
#pragma unroll
  for (int mi = 0; mi < 4; ++mi) {
#pragma unroll
    for (int r = 0; r < 4; ++r) {
      int grow = bm * 128 + wm * 64 + mi * 16 + l4 * 4 + r;
      size_t rowoff = (size_t)grow * N;
#pragma unroll
      for (int nj = 0; nj < 6; ++nj) {
        int gcol = bn * 192 + wn * 96 + nj * 16 + l15;
        float v = fmaxf(acc[mi][nj][r] * s + bv[nj], 0.f);
        C[rowoff + gcol] = f2bf(v);
      }
    }
  }
#undef STAGE_A
#undef STAGE_B
#undef LDSA
#undef LDSB
#undef MFMA12
#undef TILE_BODY
#undef SB
}

// -------- glimpse v7: v6 geometry (4 blocks/CU) + CORRECT same-XCD V sharing --------
// id = hv*64 + b  (NOT b*8+hv!): dispatch puts block i on XCD i%8, and 64%8==0, so
// all 8 hv-blocks of batch b land on XCD b%8 -> the 4 readers of each V[b]-half hit
// the same L2; per-XCD K-step window ~128KB << 4MB. v6's b*8+hv spread them across
// all 8 XCDs (192MB V re-reads from L3/HBM). + setprio around MFMA (T5: 4 blocks/CU
// at drifting phases = wave role diversity on each SIMD).
__global__ __launch_bounds__(256, 4) void k_glimpse7(
    const unsigned short* __restrict__ Vh, const unsigned short* __restrict__ Qh,
    const float* __restrict__ hmat, const float* __restrict__ hbias,
    float* __restrict__ out) {
  __shared__ __align__(16) unsigned short lV[3][64 * 64];    // 24 KB
  __shared__ __align__(16) unsigned short lQ[2][2][32 * 64]; // 16 KB
  int tid = threadIdx.x;
  int wid = tid >> 6, lane = tid & 63;
  int l15 = lane & 15, l4 = lane >> 4;

  int id = blockIdx.x;
  int b = id & 63, hv = id >> 6;  // same-XCD for all hv of a given b
  int h2 = hv >> 1, vh = hv & 1;  // heads h2, h2+4; V rows vh*64..+63

  const unsigned short* Vb = Vh + (size_t)b * 128 * 3072 + (size_t)vh * 64 * 3072;
  const unsigned short* Qb = Qh + (size_t)b * 32 * 3072;
  const float* hr0 = hmat + h2 * 3072;
  const float* hr1 = hmat + (h2 + 4) * 3072;

  f32x4 acc[2][2] = {};
  const int rr8 = tid >> 3;
  const int ch8 = tid & 7;
  const int scol8 = (ch8 ^ (rr8 & 7)) << 3;
  const int qwoff = rr8 * 64 + scol8;
  const int qc = ch8 * 8;
  const int NT = 48;

#define VSTAGE(T, SLOT)                                                          \
  {                                                                              \
    int tc = (T) < NT ? (T) : NT - 1;                                            \
    _Pragma("unroll") for (int j = 0; j < 2; ++j) {                              \
      __builtin_amdgcn_global_load_lds(                                          \
          (gas_u32*)(Vb + (size_t)(j * 32 + rr8) * 3072 + tc * 64 + scol8),      \
          (las_u32*)(&lV[SLOT][0] + j * 2048 + tid * 8), 16, 0, 0);              \
    }                                                                            \
  }

#define QLOAD(T, RQ, H)                                                          \
  {                                                                              \
    int tc = (T) < NT ? (T) : NT - 1;                                            \
    RQ = *(const uint4*)(Qb + (size_t)rr8 * 3072 + tc * 64 + qc);                \
    H[0] = ((const float4*)(hr0 + tc * 64 + qc))[0];                             \
    H[1] = ((const float4*)(hr0 + tc * 64 + qc))[1];                             \
    H[2] = ((const float4*)(hr1 + tc * 64 + qc))[0];                             \
    H[3] = ((const float4*)(hr1 + tc * 64 + qc))[1];                             \
  }

#define QWRITE(CB, RQ, H)                                                        \
  {                                                                              \
    float e0 = bf2f((unsigned short)(RQ.x & 0xffff));                            \
    float e1 = bf2f((unsigned short)(RQ.x >> 16));                               \
    float e2 = bf2f((unsigned short)(RQ.y & 0xffff));                            \
    float e3 = bf2f((unsigned short)(RQ.y >> 16));                               \
    float e4 = bf2f((unsigned short)(RQ.z & 0xffff));                            \
    float e5 = bf2f((unsigned short)(RQ.z >> 16));                               \
    float e6 = bf2f((unsigned short)(RQ.w & 0xffff));                            \
    float e7 = bf2f((unsigned short)(RQ.w >> 16));                               \
    _Pragma("unroll") for (int hh = 0; hh < 2; ++hh) {                           \
      uint4 o;                                                                   \
      o.x = f2bf(e0 * H[hh * 2].x) | ((unsigned)f2bf(e1 * H[hh * 2].y) << 16);   \
      o.y = f2bf(e2 * H[hh * 2].z) | ((unsigned)f2bf(e3 * H[hh * 2].w) << 16);   \
      o.z = f2bf(e4 * H[hh * 2 + 1].x) |                                         \
            ((unsigned)f2bf(e5 * H[hh * 2 + 1].y) << 16);                        \
      o.w = f2bf(e6 * H[hh * 2 + 1].z) |                                         \
            ((unsigned)f2bf(e7 * H[hh * 2 + 1].w) << 16);                        \
      *(uint4*)(&lQ[CB][hh][0] + qwoff) = o;                                     \
    }                                                                            \
  }

#define GMFMA(SLOT, CB)                                                          \
  {                                                                              \
    int rlv = wid * 16 + l15;                                                    \
    int s8v = rlv & 7;                                                           \
    bf16x8 af0 = *(const bf16x8*)(&lV[SLOT][0] + rlv * 64 + ((l4 ^ s8v) << 3));  \
    bf16x8 af1 =                                                                 \
        *(const bf16x8*)(&lV[SLOT][0] + rlv * 64 + (((4 | l4) ^ s8v) << 3));     \
    __builtin_amdgcn_s_setprio(1);                                               \
    _Pragma("unroll") for (int hh = 0; hh < 2; ++hh) {                           \
      _Pragma("unroll") for (int nj = 0; nj < 2; ++nj) {                         \
        int rlq = nj * 16 + l15;                                                 \
        int s8q = rlq & 7;                                                       \
        bf16x8 bq0 = *(const bf16x8*)(&lQ[CB][hh][0] + rlq * 64 +                \
                                      ((l4 ^ s8q) << 3));                        \
        bf16x8 bq1 = *(const bf16x8*)(&lQ[CB][hh][0] + rlq * 64 +                \
                                      (((4 | l4) ^ s8q) << 3));                  \
        acc[hh][nj] =                                                            \
            __builtin_amdgcn_mfma_f32_16x16x32_bf16(af0, bq0, acc[hh][nj], 0, 0, 0); \
        acc[hh][nj] =                                                            \
            __builtin_amdgcn_mfma_f32_16x16x32_bf16(af1, bq1, acc[hh][nj], 0, 0, 0); \
      }                                                                          \
    }                                                                            \
    __builtin_amdgcn_s_setprio(0);                                               \
  }

#define GBODY(T, CQ, CH, NQ, NH)                                                 \
  {                                                                              \
    QLOAD((T) + 2, NQ, NH)                                                       \
    asm volatile("s_waitcnt vmcnt(7)" ::: "memory");                             \
    asm volatile("s_waitcnt lgkmcnt(0)" ::: "memory");                           \
    __builtin_amdgcn_sched_barrier(0);                                           \
    __builtin_amdgcn_s_barrier();                                                \
    VSTAGE((T) + 2, ((T) + 2) % 3)                                               \
    QWRITE(((T) + 1) & 1, CQ, CH)                                                \
    GMFMA((T) % 3, (T) & 1)                                                      \
  }

  uint4 aq, bq_;
  float4 ah[4], bh[4];

  QLOAD(0, aq, ah)
  QLOAD(1, bq_, bh)
  VSTAGE(0, 0)
  VSTAGE(1, 1)
  asm volatile("s_waitcnt vmcnt(9)" ::: "memory");
  __builtin_amdgcn_sched_barrier(0);
  QWRITE(0, aq, ah)

  for (int t = 0; t < NT; t += 2) {
    GBODY(t, bq_, bh, aq, ah)
    GBODY(t + 1, aq, ah, bq_, bh)
  }
  asm volatile("s_waitcnt vmcnt(0) lgkmcnt(0)" ::: "memory");

#pragma unroll
  for (int hh = 0; hh < 2; ++hh) {
    int h = h2 + hh * 4;
    float hb = hbias[h];
    float* ob = out + (size_t)(b * 8 + h) * 128 * 32;
#pragma unroll
    for (int nj = 0; nj < 2; ++nj)
#pragma unroll
      for (int r = 0; r < 4; ++r) {
        int row = vh * 64 + wid * 16 + l4 * 4 + r;
        int col = nj * 16 + l15;
        ob[row * 32 + col] = acc[hh][nj][r] + hb;
      }
  }
#undef VSTAGE
#undef QLOAD
#undef QWRITE
#undef GMFMA
#undef GBODY
}

extern "C" void kernel_launch(void* const* d_in, const int* in_sizes, int n_in,
                              void* d_out, int out_size, void* d_ws, size_t ws_size,
                              hipStream_t stream) {
  const float* v = (const float*)d_in[0];
  const float* q = (const float*)d_in[1];
  const float* v_w = (const float*)d_in[2];
  const float* v_g = (const float*)d_in[3];
  const float* v_b = (const float*)d_in[4];
  const float* q_w = (const float*)d_in[5];
  const float* q_g = (const float*)d_in[6];
  const float* q_b = (const float*)d_in[7];
  const float* hmat = (const float*)d_in[8];
  const float* hbias = (const float*)d_in[9];
  float* out = (float*)d_out;

  const size_t n_v = 16777216;   // 64*128*2048
  const size_t n_vw = 6291456;   // 3072*2048
  const size_t n_q = 2097152;    // 64*32*1024
  const size_t n_qw = 3145728;   // 3072*1024
  const size_t n_vh = 25165824;  // 8192*3072
  const size_t n_qh = 6291456;   // 2048*3072

  char* ws = (char*)d_ws;
  float* ss = (float*)ws;
  size_t off = 256;
  unsigned short* v_bf = (unsigned short*)(ws + off);  off += n_v * 2;
  unsigned short* vw_bf = (unsigned short*)(ws + off); off += n_vw * 2;
  unsigned short* q_bf = (unsigned short*)(ws + off);  off += n_q * 2;
  unsigned short* qw_bf = (unsigned short*)(ws + off); off += n_qw * 2;
  unsigned short* v_h = (unsigned short*)(ws + off);   off += n_vh * 2;
  unsigned short* q_h = (unsigned short*)(ws + off);   off += n_qh * 2;

  (void)hipMemsetAsync(ss, 0, 8, stream);
  k_prep<<<1536, 256, 0, stream>>>(v, q, v_w, q_w, v_bf, q_bf, vw_bf, qw_bf, ss);

  // merged GEMM1 (1024 blocks) + GEMM2 (256 blocks), cache-tier XCD remap (frozen)
  k_gemm_cmb<<<1280, 256, 0, stream>>>(v_bf, vw_bf, v_b, v_g, ss + 0, v_h,
                                       q_bf, qw_bf, q_b, q_g, ss + 1, q_h);

  k_glimpse7<<<512, 256, 0, stream>>>(v_h, q_h, hmat, hbias, out);
}